// Round 3
// baseline (51.856 us; speedup 1.0000x reference)
//
#include <hip/hip_runtime.h>

// B=32, R=3136 (=56*56), O=20, D=32. Memory-bound: ~294 MB traffic.
#define NB 32
#define NR 3136
#define NO 20
#define ND 32
#define RPB 32            // rays per block; each half-wave handles 2 rays
#define BLOCK 512

__global__ __launch_bounds__(BLOCK) void ray_composite(
    const float* __restrict__ form,    // [B,R,O,D]
    const float* __restrict__ depth,   // [B,R,O]
    const float* __restrict__ trans,   // [B,R,O]
    float* __restrict__ out_res,       // [B,D,H,W]
    float* __restrict__ out_pond)      // [B,R,O]
{
  __shared__ float stage[2 * RPB * NO];   // depth [0,640), trans [640,1280)
  __shared__ float res_lds[RPB][36];      // pad 32->36 keeps float4 align
  __shared__ float pond_lds[RPB * NO];

  const int t    = threadIdx.x;
  const int rib  = t >> 5;                // 0..15; handles rays rib, rib+16
  const int lane = t & 31;
  const int ray0 = blockIdx.x * RPB;
  const int b    = ray0 / NR;             // RPB | NR: no batch straddle
  const int r0   = ray0 - b * NR;

  // ---- phase 0: coalesced float4 staging of depth/trans ----
  if (t < 160)
    reinterpret_cast<float4*>(stage)[t] =
        reinterpret_cast<const float4*>(depth + (size_t)ray0 * NO)[t];
  else if (t < 320)
    reinterpret_cast<float4*>(stage + RPB * NO)[t - 160] =
        reinterpret_cast<const float4*>(trans + (size_t)ray0 * NO)[t - 160];
  __syncthreads();

  // ---- phase 1: ponderation for 2 rays per half-wave ----
  float dA = 0.f, tA = 0.f, dB = 0.f, tB = 0.f;
  if (lane < NO) {
    dA = stage[rib * NO + lane];
    tA = stage[RPB * NO + rib * NO + lane];
    dB = stage[(rib + 16) * NO + lane];
    tB = stage[RPB * NO + (rib + 16) * NO + lane];
  }
  float accA = 0.f, accB = 0.f;
#pragma unroll
  for (int j = 0; j < NO; ++j) {
    const float djA = __shfl(dA, j, 32), tjA = __shfl(tA, j, 32);
    const float djB = __shfl(dB, j, 32), tjB = __shfl(tB, j, 32);
    if (j != lane) {
      accA += tjA / (1.f + __expf(-1000.f * (dA - djA)));
      accB += tjB / (1.f + __expf(-1000.f * (dB - djB)));
    }
  }
  float pondA = __expf(accA) * (1.f - __expf(tA));
  float pondB = __expf(accB) * (1.f - __expf(tB));
  if (lane >= NO) { pondA = 0.f; pondB = 0.f; }
  if (lane < NO) {
    pond_lds[rib * NO + lane]        = pondA;
    pond_lds[(rib + 16) * NO + lane] = pondB;
  }

  // ---- phase 2: res[d] = sum_o pond[o]*form[o][d]; 10 float4 in flight ----
  const int c  = lane & 7;
  const int og = lane >> 3;
  const float* fA = form + (size_t)(ray0 + rib) * (NO * ND);
  const float* fB = form + (size_t)(ray0 + rib + 16) * (NO * ND);
  float4 aA = make_float4(0.f, 0.f, 0.f, 0.f);
  float4 aB = make_float4(0.f, 0.f, 0.f, 0.f);
#pragma unroll
  for (int k = 0; k < 5; ++k) {
    const int o = og + 4 * k;
    const float pA = __shfl(pondA, o, 32);
    const float pB = __shfl(pondB, o, 32);
    const float4 vA = *reinterpret_cast<const float4*>(fA + o * ND + c * 4);
    const float4 vB = *reinterpret_cast<const float4*>(fB + o * ND + c * 4);
    aA.x += pA * vA.x; aA.y += pA * vA.y; aA.z += pA * vA.z; aA.w += pA * vA.w;
    aB.x += pB * vB.x; aB.y += pB * vB.y; aB.z += pB * vB.z; aB.w += pB * vB.w;
  }
#pragma unroll
  for (int m = 8; m <= 16; m <<= 1) {
    aA.x += __shfl_xor(aA.x, m, 32); aA.y += __shfl_xor(aA.y, m, 32);
    aA.z += __shfl_xor(aA.z, m, 32); aA.w += __shfl_xor(aA.w, m, 32);
    aB.x += __shfl_xor(aB.x, m, 32); aB.y += __shfl_xor(aB.y, m, 32);
    aB.z += __shfl_xor(aB.z, m, 32); aB.w += __shfl_xor(aB.w, m, 32);
  }
  if (lane < 8) {
    *reinterpret_cast<float4*>(&res_lds[rib][lane * 4])      = aA;
    *reinterpret_cast<float4*>(&res_lds[rib + 16][lane * 4]) = aB;
  }
  __syncthreads();

  // ---- phase 3: full-line coalesced stores ----
  // result: per d, 32 consecutive floats (128B line per block) via float2
  {
    const int d = t >> 4;       // 0..31
    const int j = t & 15;       // ray pair (2j, 2j+1)
    float2 v = make_float2(res_lds[2 * j][d], res_lds[2 * j + 1][d]);
    *reinterpret_cast<float2*>(out_res + (size_t)b * (ND * NR) +
                               (size_t)d * NR + r0 + 2 * j) = v;
  }
  // ponderation: contiguous 2560B per block via float2
  if (t < RPB * NO / 2) {
    float2 v = make_float2(pond_lds[2 * t], pond_lds[2 * t + 1]);
    *reinterpret_cast<float2*>(out_pond + (size_t)ray0 * NO + 2 * t) = v;
  }
}

extern "C" void kernel_launch(void* const* d_in, const int* in_sizes, int n_in,
                              void* d_out, int out_size, void* d_ws, size_t ws_size,
                              hipStream_t stream) {
  const float* form  = (const float*)d_in[0];
  const float* depth = (const float*)d_in[1];
  const float* trans = (const float*)d_in[2];

  float* out_res  = (float*)d_out;
  float* out_pond = out_res + (size_t)NB * ND * NR;

  dim3 grid((NB * NR) / RPB);   // 3136
  dim3 block(BLOCK);            // 512
  ray_composite<<<grid, block, 0, stream>>>(form, depth, trans, out_res, out_pond);
}